// Round 5
// baseline (498.758 us; speedup 1.0000x reference)
//
#include <hip/hip_runtime.h>
#include <hip/hip_cooperative_groups.h>

namespace cg = cooperative_groups;

#define N_NODES 4096
#define HID 512
#define HEADS 8
#define DH 64
#define EPS 1e-5f
#define MAXD 128

typedef __attribute__((ext_vector_type(8))) short bf16x8;
typedef __attribute__((ext_vector_type(4))) float f32x4;

__device__ __forceinline__ unsigned short f2bf(float f) {
    unsigned int u = __float_as_uint(f);
    unsigned int r = (u + 0x7FFFu + ((u >> 16) & 1u)) >> 16;   // RNE
    return (unsigned short)r;
}
__device__ __forceinline__ float blo(unsigned int u) {        // low bf16 -> f32
    return __uint_as_float(u << 16);
}
__device__ __forceinline__ float bhi(unsigned int u) {        // high bf16 -> f32
    return __uint_as_float(u & 0xffff0000u);
}

__device__ __forceinline__ void gld_lds16(const void* g, void* l) {
    __builtin_amdgcn_global_load_lds(
        (const __attribute__((address_space(1))) unsigned int*)g,
        (__attribute__((address_space(3))) unsigned int*)l, 16, 0, 0);
}

// ---------------------------------------------------------------------------
// bf16 MFMA GEMM tile (device fn): C[M x Nc] = X[M x K] @ W^T (Wt K-major).
// R5: back to the PROVEN R0 single-buffer core (R1 dbuf and R4 counted-vmcnt
// pipelines were both neutral -> inner-loop latency is NOT the bottleneck;
// the dispatch chain is — see megaB).
// TM x 64 tile, BK=64, 256 threads = 4 waves stacked on M.
// Swizzle: global k-chunk (tid&7)^(srow&7) -> LDS slot s of row r holds
// chunk s^(r&7); read slot (half*4+lq)^(lc&7) -> conflict-free b128.
// EPI: 0 bias->bf16 ; 1 bias+relu->bf16 ; 2 bias+res(f32)->f32 + stats ;
//      3 bias+res(bf16)->f32 + stats
// ---------------------------------------------------------------------------
template<int TM, int EPI>
__device__ __forceinline__ void gemm_tile(
    const unsigned short* __restrict__ Xb, const unsigned short* __restrict__ Wt,
    const float* __restrict__ bias, const float* __restrict__ res,
    const unsigned short* __restrict__ resb,
    float* __restrict__ outf, unsigned short* __restrict__ outb,
    float* __restrict__ sum, float* __restrict__ sumsq,
    int K, int Nc, int bx, int by,
    unsigned short* As, unsigned short* Bs)
{
    constexpr int WM = TM / 64;                      // 2 (TM=128) or 1 (TM=64)
    const int tid = threadIdx.x;
    const int lane = tid & 63;
    const int wv = tid >> 6;
    const int m0 = by * TM, n0 = bx * 64;
    const int lc = lane & 15, lq = lane >> 4;
    const int rowbase = wv * (WM * 16);

    const int srow = tid >> 3;                       // 0..31
    const int schunk = (tid & 7) ^ (srow & 7);       // swizzled global k-chunk
    unsigned short* ldsA = As + tid * 8;
    unsigned short* ldsB = Bs + tid * 8;
    const int rs0 = lq ^ (lc & 7);
    const int rs1 = (4 + lq) ^ (lc & 7);

    f32x4 acc[WM][4] = {};

    for (int k0 = 0; k0 < K; k0 += 64) {
        const unsigned short* gA = Xb + (size_t)(m0 + srow) * K + k0 + schunk * 8;
        const unsigned short* gB = Wt + (size_t)(n0 + srow) * K + k0 + schunk * 8;
        #pragma unroll
        for (int p = 0; p < TM / 32; ++p)
            gld_lds16(gA + (size_t)(p * 32) * K, ldsA + p * 2048);
        #pragma unroll
        for (int p = 0; p < 2; ++p)
            gld_lds16(gB + (size_t)(p * 32) * K, ldsB + p * 2048);
        __syncthreads();

        #pragma unroll
        for (int hh = 0; hh < 2; ++hh) {
            const int rs = hh ? rs1 : rs0;
            bf16x8 af[WM], bfr[4];
            #pragma unroll
            for (int i = 0; i < WM; ++i)
                af[i] = *(const bf16x8*)&As[(rowbase + i * 16 + lc) * 64 + rs * 8];
            #pragma unroll
            for (int j = 0; j < 4; ++j)
                bfr[j] = *(const bf16x8*)&Bs[(j * 16 + lc) * 64 + rs * 8];
            #pragma unroll
            for (int i = 0; i < WM; ++i)
                #pragma unroll
                for (int j = 0; j < 4; ++j)
                    acc[i][j] = __builtin_amdgcn_mfma_f32_16x16x32_bf16(af[i], bfr[j], acc[i][j], 0, 0, 0);
        }
        __syncthreads();
    }

    float cs[4] = {}, css[4] = {};
    #pragma unroll
    for (int i = 0; i < WM; ++i) {
        #pragma unroll
        for (int j = 0; j < 4; ++j) {
            const int gr0 = m0 + rowbase + i * 16 + lq * 4;
            const int gc = n0 + j * 16 + lc;
            const float bi = bias[gc];
            #pragma unroll
            for (int r = 0; r < 4; ++r) {
                float val = acc[i][j][r] + bi;
                size_t off = (size_t)(gr0 + r) * Nc + gc;
                if (EPI == 0)      outb[off] = f2bf(val);
                else if (EPI == 1) outb[off] = f2bf(fmaxf(val, 0.f));
                else {
                    if (EPI == 2) val += res[off];
                    else          val += blo((unsigned int)resb[off]);
                    outf[off] = val;
                    cs[j] += val; css[j] += val * val;
                }
            }
        }
    }
    if (EPI >= 2) {
        #pragma unroll
        for (int j = 0; j < 4; ++j) {
            float s = cs[j], ss = css[j];
            s += __shfl_xor(s, 16); s += __shfl_xor(s, 32);
            ss += __shfl_xor(ss, 16); ss += __shfl_xor(ss, 32);
            if (lq == 0) {
                const int gc = n0 + j * 16 + lc;
                atomicAdd(&sum[gc], s);
                atomicAdd(&sumsq[gc], ss);
            }
        }
    }
}

// Standalone GEMM kernel (QKV projection).
template<int TM, int EPI>
__global__ __launch_bounds__(256) void gemm_bf16(
    const unsigned short* __restrict__ Xb, const unsigned short* __restrict__ Wt,
    const float* __restrict__ bias,
    unsigned short* __restrict__ outb, int K, int Nc)
{
    __shared__ __align__(16) unsigned short As[TM * 64];
    __shared__ __align__(16) unsigned short Bs[64 * 64];
    gemm_tile<TM, EPI>(Xb, Wt, bias, nullptr, nullptr, nullptr, outb,
                       nullptr, nullptr, K, Nc, blockIdx.x, blockIdx.y, As, Bs);
}

// BatchNorm apply for one 256-thread item (i indexes float4 elements).
__device__ __forceinline__ void bn_item(
    const float4* __restrict__ x, const float* __restrict__ sum,
    const float* __restrict__ sumsq, const float* __restrict__ g,
    const float* __restrict__ b, float4* __restrict__ yf,
    uint2* __restrict__ yb, int i)
{
    const int c4 = i & 127;
    const float4 s4 = ((const float4*)sum)[c4];
    const float4 q4 = ((const float4*)sumsq)[c4];
    const float4 g4 = ((const float4*)g)[c4];
    const float4 b4 = ((const float4*)b)[c4];
    const float4 xv = x[i];
    const float kN = 1.0f / N_NODES;
    float4 r;
    { float m = s4.x * kN; r.x = g4.x * (xv.x - m) * rsqrtf(q4.x * kN - m * m + EPS) + b4.x; }
    { float m = s4.y * kN; r.y = g4.y * (xv.y - m) * rsqrtf(q4.y * kN - m * m + EPS) + b4.y; }
    { float m = s4.z * kN; r.z = g4.z * (xv.z - m) * rsqrtf(q4.z * kN - m * m + EPS) + b4.z; }
    { float m = s4.w * kN; r.w = g4.w * (xv.w - m) * rsqrtf(q4.w * kN - m * m + EPS) + b4.w; }
    if (yf) yf[i] = r;
    if (yb) {
        uint2 p;
        p.x = (unsigned int)f2bf(r.x) | ((unsigned int)f2bf(r.y) << 16);
        p.y = (unsigned int)f2bf(r.z) | ((unsigned int)f2bf(r.w) << 16);
        yb[i] = p;
    }
}

// ---------------------------------------------------------------------------
// megaB (cooperative, 512 blocks = exactly 2/CU): the whole post-attention
// chain in ONE dispatch. R5 theory: four rounds of GEMM-schedule changes
// were all neutral -> the ~130 us of slack is in the 8-deep dispatch chain
// (launch ramp + full-device drain per kernel), not in kernel bodies.
// Phases: O+res+BN1stats | sync | BN1 apply | sync | FFN1+relu | sync |
//         FFN2+res+BN2stats | sync | BN2 apply -> out.
// Replaces 5 dispatches with 1 (+4 grid syncs).
// ---------------------------------------------------------------------------
__global__ __launch_bounds__(256, 2) void megaB(
    const unsigned short* __restrict__ o_bf, const unsigned short* __restrict__ woT,
    const float* __restrict__ bo, const float* __restrict__ h,
    float* __restrict__ x1,
    const float* __restrict__ g1, const float* __restrict__ b1g,
    unsigned short* __restrict__ xb1_b,
    const unsigned short* __restrict__ w1T, const float* __restrict__ b1,
    unsigned short* __restrict__ t_b,
    const unsigned short* __restrict__ w2T, const float* __restrict__ b2,
    float* __restrict__ x2,
    const float* __restrict__ g2, const float* __restrict__ b2g,
    float* __restrict__ out, float* __restrict__ st)
{
    __shared__ __align__(16) unsigned short smem[128 * 64 + 64 * 64];
    cg::grid_group grid = cg::this_grid();
    const int bid = blockIdx.x;          // 0..511
    const int tid = threadIdx.x;

    // Phase 1: O projection + residual(h,f32) -> x1 + BN1 stats.
    // 512 tiles of 64x64: bx = bid&7 (8 n-tiles), by = bid>>3 (64 m-tiles).
    gemm_tile<64, 2>(o_bf, woT, bo, h, nullptr, x1, nullptr, st, st + 512,
                     512, 512, bid & 7, bid >> 3, smem, smem + 64 * 64);
    grid.sync();

    // Phase 2: BN1 apply -> xb1_b (bf16). 524288 float4 over 131072 threads.
    #pragma unroll
    for (int it = 0; it < 4; ++it)
        bn_item((const float4*)x1, st, st + 512, g1, b1g, nullptr,
                (uint2*)xb1_b, (it * 512 + bid) * 256 + tid);
    grid.sync();

    // Phase 3: FFN1 + relu -> t_b. 512 tiles of 128x64: bx=bid&15, by=bid>>4.
    gemm_tile<128, 1>(xb1_b, w1T, b1, nullptr, nullptr, nullptr, t_b,
                      nullptr, nullptr, 512, 1024, bid & 15, bid >> 4,
                      smem, smem + 128 * 64);
    grid.sync();

    // Phase 4: FFN2 + residual(xb1,bf16) -> x2 + BN2 stats. 512 tiles 64x64.
    gemm_tile<64, 3>(t_b, w2T, b2, nullptr, xb1_b, x2, nullptr,
                     st + 1024, st + 1536, 1024, 512, bid & 7, bid >> 3,
                     smem, smem + 64 * 64);
    grid.sync();

    // Phase 5: BN2 apply -> out (f32).
    #pragma unroll
    for (int it = 0; it < 4; ++it)
        bn_item((const float4*)x2, st + 1024, st + 1536, g2, b2g,
                (float4*)out, nullptr, (it * 512 + bid) * 256 + tid);
}

// ---------------------------------------------------------------------------
// Fused prep: z=0..5 weight transposes, z=6 h->bf16, z=7 bias concat + zero,
// z=8 adjacency CSR build (rides prep's idle HBM).
// ---------------------------------------------------------------------------
__global__ __launch_bounds__(256) void prep_all(
    const float* __restrict__ Wq, const float* __restrict__ Wk,
    const float* __restrict__ Wv, const float* __restrict__ Wo,
    const float* __restrict__ W1, const float* __restrict__ W2,
    const float* __restrict__ h,
    const float* __restrict__ bq, const float* __restrict__ bk,
    const float* __restrict__ bv,
    unsigned short* __restrict__ wqkvT, unsigned short* __restrict__ woT,
    unsigned short* __restrict__ w1T, unsigned short* __restrict__ w2T,
    unsigned int* __restrict__ hb, float* __restrict__ bqkv,
    float* __restrict__ st,
    const float* __restrict__ Adj, int* __restrict__ adjIdx,
    int* __restrict__ adjCnt)
{
    const int z = blockIdx.z;
    if (z < 6) {
        const float* in; unsigned short* out; int R, C;
        switch (z) {
            case 0: in = Wq; out = wqkvT;          R = 512;  C = 512;  break;
            case 1: in = Wk; out = wqkvT + 262144; R = 512;  C = 512;  break;
            case 2: in = Wv; out = wqkvT + 524288; R = 512;  C = 512;  break;
            case 3: in = Wo; out = woT;            R = 512;  C = 512;  break;
            case 4: in = W1; out = w1T;            R = 512;  C = 1024; break;
            default: in = W2; out = w2T;           R = 1024; C = 512;  break;
        }
        const int bc = blockIdx.x * 32, br = blockIdx.y * 32;
        if (bc >= C || br >= R) return;
        __shared__ float tile[32][33];
        const int tx = threadIdx.x & 31, ty = threadIdx.x >> 5;
        #pragma unroll
        for (int r = ty; r < 32; r += 8)
            tile[r][tx] = in[(size_t)(br + r) * C + bc + tx];
        __syncthreads();
        #pragma unroll
        for (int r = ty; r < 32; r += 8)
            out[(size_t)(bc + r) * R + br + tx] = f2bf(tile[tx][r]);
    } else if (z == 6) {
        const int blk = blockIdx.y * 32 + blockIdx.x;
        const int i = blk * 512 + threadIdx.x * 2;   // float4 index (524288 total)
        const float4* in4 = (const float4*)h;
        #pragma unroll
        for (int u = 0; u < 2; ++u) {
            float4 f = in4[i + u];
            hb[(i + u) * 2]     = (unsigned int)f2bf(f.x) | ((unsigned int)f2bf(f.y) << 16);
            hb[(i + u) * 2 + 1] = (unsigned int)f2bf(f.z) | ((unsigned int)f2bf(f.w) << 16);
        }
    } else if (z == 7) {
        const int blk = blockIdx.y * 32 + blockIdx.x;
        const int i = blk * 256 + threadIdx.x;
        if (i < 1536) bqkv[i] = i < 512 ? bq[i] : (i < 1024 ? bk[i - 512] : bv[i - 1024]);
        if (i < 2048) st[i] = 0.0f;
    } else {
        // ---- adjacency CSR build: 1024 blocks x 4 nodes, 4 waves per row ----
        const int tid = threadIdx.x;
        const int lane = tid & 63;
        const int wv4 = tid >> 6;
        __shared__ int s_cnt[4];
        const unsigned long long lt = (1ull << lane) - 1ull;
        const int blk = blockIdx.y * 32 + blockIdx.x;    // 0..1023
        #pragma unroll
        for (int it = 0; it < 4; ++it) {
            const int n = blk * 4 + it;
            const float4* r4 = (const float4*)(Adj + (size_t)n * N_NODES);
            float4 av[4];
            #pragma unroll
            for (int t = 0; t < 4; ++t)
                av[t] = r4[wv4 * 256 + t * 64 + lane];
            int cnt = 0;
            #pragma unroll
            for (int t = 0; t < 4; ++t) {
                #pragma unroll
                for (int b = 0; b < 4; ++b) {
                    float vb = (b == 0) ? av[t].x : (b == 1) ? av[t].y : (b == 2) ? av[t].z : av[t].w;
                    cnt += __popcll(__ballot(vb > 0.0f));
                }
            }
            if (lane == 0) s_cnt[wv4] = cnt;
            __syncthreads();
            int base = 0, total = 0;
            #pragma unroll
            for (int w = 0; w < 4; ++w) {
                if (w < wv4) base += s_cnt[w];
                total += s_cnt[w];
            }
            #pragma unroll
            for (int t = 0; t < 4; ++t) {
                #pragma unroll
                for (int b = 0; b < 4; ++b) {
                    float vb = (b == 0) ? av[t].x : (b == 1) ? av[t].y : (b == 2) ? av[t].z : av[t].w;
                    unsigned long long m = __ballot(vb > 0.0f);
                    if (vb > 0.0f) {
                        int p = base + __popcll(m & lt);
                        if (p < MAXD) adjIdx[n * MAXD + p] = wv4 * 1024 + t * 256 + lane * 4 + b;
                    }
                    base += __popcll(m);
                }
            }
            if (tid == 0) adjCnt[n] = total < MAXD ? total : MAXD;
            __syncthreads();   // protect s_cnt before next node iteration
        }
    }
}

// ---------------------------------------------------------------------------
// Sparse attention v6: adjacency precomputed (prep z=8). Dual-head gather
// loops with 1-deep prefetch (0 conflicts). Stays standalone: it needs the
// 4096-block high-occupancy shape a cooperative launch can't give.
// ---------------------------------------------------------------------------
__global__ __launch_bounds__(256) void sparse_attn6(
    const int* __restrict__ adjIdx, const int* __restrict__ adjCnt,
    const unsigned short* __restrict__ qkv, unsigned short* __restrict__ o)
{
    const int n = blockIdx.x;
    const int tid = threadIdx.x;
    const int wv = tid >> 6, lane = tid & 63;

    __shared__ int s_idx[MAXD];
    __shared__ float s_p[8][MAXD];

    const int d = adjCnt[n];
    if (tid < d) s_idx[tid] = adjIdx[n * MAXD + tid];
    __syncthreads();

    // ---- scores ----
    const int jl = lane >> 3;
    const int dgs = lane & 7;
    const int jl2 = lane >> 4;
    const int dga = lane & 15;
    const int h0 = wv, h1 = wv + 4;

    const unsigned short* qp = qkv + (size_t)n * 1536 + dgs * 8;
    uint4 qa = *(const uint4*)(qp + h0 * 64);
    uint4 qb = *(const uint4*)(qp + h1 * 64);
    const float a0 = blo(qa.x), a1 = bhi(qa.x), a2 = blo(qa.y), a3 = bhi(qa.y);
    const float a4 = blo(qa.z), a5 = bhi(qa.z), a6 = blo(qa.w), a7 = bhi(qa.w);
    const float b0 = blo(qb.x), b1 = bhi(qb.x), b2 = blo(qb.y), b3 = bhi(qb.y);
    const float b4 = blo(qb.z), b5 = bhi(qb.z), b6 = blo(qb.w), b7 = bhi(qb.w);

    uint4 ka = {0, 0, 0, 0}, kb = {0, 0, 0, 0};
    if (jl < d) {
        const unsigned short* p = qkv + (size_t)s_idx[jl] * 1536 + 512 + dgs * 8;
        ka = *(const uint4*)(p + h0 * 64);
        kb = *(const uint4*)(p + h1 * 64);
    }
    for (int j0 = 0; j0 < d; j0 += 8) {
        const uint4 ca = ka, cb = kb;
        const int jn = j0 + 8 + jl;
        if (jn < d) {
            const unsigned short* p = qkv + (size_t)s_idx[jn] * 1536 + 512 + dgs * 8;
            ka = *(const uint4*)(p + h0 * 64);
            kb = *(const uint4*)(p + h1 * 64);
        }
        const int jc = j0 + jl;
        float s0 = 0.f, s1 = 0.f;
        if (jc < d) {
            s0 = a0 * blo(ca.x) + a1 * bhi(ca.x) + a2 * blo(ca.y) + a3 * bhi(ca.y)
               + a4 * blo(ca.z) + a5 * bhi(ca.z) + a6 * blo(ca.w) + a7 * bhi(ca.w);
            s1 = b0 * blo(cb.x) + b1 * bhi(cb.x) + b2 * blo(cb.y) + b3 * bhi(cb.y)
               + b4 * blo(cb.z) + b5 * bhi(cb.z) + b6 * blo(cb.w) + b7 * bhi(cb.w);
        }
        s0 += __shfl_xor(s0, 1); s1 += __shfl_xor(s1, 1);
        s0 += __shfl_xor(s0, 2); s1 += __shfl_xor(s1, 2);
        s0 += __shfl_xor(s0, 4); s1 += __shfl_xor(s1, 4);
        if (dgs == 0 && jc < d) {
            s_p[h0][jc] = s0 * 0.125f;
            s_p[h1][jc] = s1 * 0.125f;
        }
    }

    float inv0, inv1;
    #pragma unroll
    for (int hh = 0; hh < 2; ++hh) {
        float* sp = s_p[hh ? h1 : h0];
        float mx = -1e30f;
        for (int j = lane; j < d; j += 64) mx = fmaxf(mx, sp[j]);
        #pragma unroll
        for (int off = 32; off; off >>= 1) mx = fmaxf(mx, __shfl_xor(mx, off));
        float sum = 0.f;
        for (int j = lane; j < d; j += 64) {
            float e = __expf(sp[j] - mx);
            sp[j] = e;
            sum += e;
        }
        #pragma unroll
        for (int off = 32; off; off >>= 1) sum += __shfl_xor(sum, off);
        if (hh) inv1 = 1.0f / sum; else inv0 = 1.0f / sum;
    }

    float x0 = 0.f, x1 = 0.f, x2 = 0.f, x3 = 0.f;
    float y0 = 0.f, y1 = 0.f, y2 = 0.f, y3 = 0.f;
    uint2 va = {0, 0}, vb = {0, 0};
    if (jl2 < d) {
        const unsigned short* p = qkv + (size_t)s_idx[jl2] * 1536 + 1024 + dga * 4;
        va = *(const uint2*)(p + h0 * 64);
        vb = *(const uint2*)(p + h1 * 64);
    }
    for (int j0 = 0; j0 < d; j0 += 4) {
        const uint2 ca = va, cb = vb;
        const int jn = j0 + 4 + jl2;
        if (jn < d) {
            const unsigned short* p = qkv + (size_t)s_idx[jn] * 1536 + 1024 + dga * 4;
            va = *(const uint2*)(p + h0 * 64);
            vb = *(const uint2*)(p + h1 * 64);
        }
        const int jc = j0 + jl2;
        if (jc < d) {
            const float p0 = s_p[h0][jc], p1 = s_p[h1][jc];
            x0 += p0 * blo(ca.x); x1 += p0 * bhi(ca.x);
            x2 += p0 * blo(ca.y); x3 += p0 * bhi(ca.y);
            y0 += p1 * blo(cb.x); y1 += p1 * bhi(cb.x);
            y2 += p1 * blo(cb.y); y3 += p1 * bhi(cb.y);
        }
    }
    x0 += __shfl_xor(x0, 16); x0 += __shfl_xor(x0, 32);
    x1 += __shfl_xor(x1, 16); x1 += __shfl_xor(x1, 32);
    x2 += __shfl_xor(x2, 16); x2 += __shfl_xor(x2, 32);
    x3 += __shfl_xor(x3, 16); x3 += __shfl_xor(x3, 32);
    y0 += __shfl_xor(y0, 16); y0 += __shfl_xor(y0, 32);
    y1 += __shfl_xor(y1, 16); y1 += __shfl_xor(y1, 32);
    y2 += __shfl_xor(y2, 16); y2 += __shfl_xor(y2, 32);
    y3 += __shfl_xor(y3, 16); y3 += __shfl_xor(y3, 32);
    if (jl2 == 0) {
        uint2 w0, w1;
        w0.x = (unsigned int)f2bf(x0 * inv0) | ((unsigned int)f2bf(x1 * inv0) << 16);
        w0.y = (unsigned int)f2bf(x2 * inv0) | ((unsigned int)f2bf(x3 * inv0) << 16);
        w1.x = (unsigned int)f2bf(y0 * inv1) | ((unsigned int)f2bf(y1 * inv1) << 16);
        w1.y = (unsigned int)f2bf(y2 * inv1) | ((unsigned int)f2bf(y3 * inv1) << 16);
        *(uint2*)(o + (size_t)n * 512 + h0 * 64 + dga * 4) = w0;
        *(uint2*)(o + (size_t)n * 512 + h1 * 64 + dga * 4) = w1;
    }
}

// ---------------------------------------------------------------------------

extern "C" void kernel_launch(void* const* d_in, const int* in_sizes, int n_in,
                              void* d_out, int out_size, void* d_ws, size_t ws_size,
                              hipStream_t stream)
{
    const float* A   = (const float*)d_in[0];
    const float* h   = (const float*)d_in[1];
    const float* Wq  = (const float*)d_in[2];
    const float* bq  = (const float*)d_in[3];
    const float* Wk  = (const float*)d_in[4];
    const float* bk  = (const float*)d_in[5];
    const float* Wv  = (const float*)d_in[6];
    const float* bv  = (const float*)d_in[7];
    const float* Wo  = (const float*)d_in[8];
    const float* bo  = (const float*)d_in[9];
    const float* g1  = (const float*)d_in[10];
    const float* b1g = (const float*)d_in[11];
    const float* g2  = (const float*)d_in[12];
    const float* b2g = (const float*)d_in[13];
    const float* W1  = (const float*)d_in[14];
    const float* b1  = (const float*)d_in[15];
    const float* W2  = (const float*)d_in[16];
    const float* b2  = (const float*)d_in[17];
    float* out = (float*)d_out;

    float* ws = (float*)d_ws;
    unsigned short* hb    = (unsigned short*)(ws);               // 4096x512 bf16
    unsigned short* qkvb  = (unsigned short*)(ws + 1048576);     // 4096x1536 bf16
    unsigned short* o_bf  = (unsigned short*)(ws + 4194304);     // 4096x512 bf16
    unsigned short* wqkvT = (unsigned short*)(ws + 5242880);     // 1536x512 bf16
    unsigned short* woT   = (unsigned short*)(ws + 5636096);     // 512x512 bf16
    unsigned short* w1T   = (unsigned short*)(ws + 5767168);     // 1024x512 bf16
    unsigned short* w2T   = (unsigned short*)(ws + 6029312);     // 512x1024 bf16
    unsigned short* t_b   = (unsigned short*)(ws + 6291456);     // 4096x1024 bf16
    float* x1   = ws + 8388608;                                   // 4096x512 f32
    float* x2   = ws + 10485760;                                  // 4096x512 f32
    unsigned short* xb1_b = (unsigned short*)(ws + 12582912);    // 4096x512 bf16
    float* bqkv = ws + 13631488;                                  // 1536
    float* st   = ws + 13633024;                                  // 2048
    // Adjacency CSR aliased into the head of the t_b region: written in
    // prep (z=8), read only by sparse_attn6, dead before FFN1 writes t_b.
    int* adjIdx = (int*)(ws + 6291456);                           // 4096x128 int
    int* adjCnt = (int*)(ws + 6815744);                           // 4096 int

    // --- fused prep (+ adjacency scan riding prep's idle HBM, z=8) ---
    prep_all<<<dim3(32, 32, 9), dim3(256), 0, stream>>>(
        Wq, Wk, Wv, Wo, W1, W2, h, bq, bk, bv,
        wqkvT, woT, w1T, w2T, (unsigned int*)hb, bqkv, st,
        A, adjIdx, adjCnt);

    // --- fused QKV projection: 768 blocks ---
    gemm_bf16<128, 0><<<dim3(24, 32), dim3(256), 0, stream>>>(
        hb, wqkvT, bqkv, qkvb, 512, 1536);

    // --- sparse masked attention (precomputed adjacency) ---
    sparse_attn6<<<dim3(N_NODES), dim3(256), 0, stream>>>(adjIdx, adjCnt, qkvb, o_bf);

    // --- megaB: O+BN1stats | BN1 | FFN1 | FFN2+BN2stats | BN2 -> out ---
    {
        const unsigned short* a0 = o_bf;  const unsigned short* a1 = woT;
        const float* a2 = bo;             const float* a3 = h;
        float* a4 = x1;
        const float* a5 = g1;             const float* a6 = b1g;
        unsigned short* a7 = xb1_b;
        const unsigned short* a8 = w1T;   const float* a9 = b1;
        unsigned short* a10 = t_b;
        const unsigned short* a11 = w2T;  const float* a12 = b2;
        float* a13 = x2;
        const float* a14 = g2;            const float* a15 = b2g;
        float* a16 = out;                 float* a17 = st;
        void* margs[] = { &a0, &a1, &a2, &a3, &a4, &a5, &a6, &a7, &a8, &a9,
                          &a10, &a11, &a12, &a13, &a14, &a15, &a16, &a17 };
        hipLaunchCooperativeKernel((void*)megaB, dim3(512), dim3(256),
                                   margs, 0, stream);
    }

    (void)in_sizes; (void)n_in; (void)out_size; (void)ws_size;
}

// Round 7
// 247.756 us; speedup vs baseline: 2.0131x; 2.0131x over previous
//
#include <hip/hip_runtime.h>

#define N_NODES 4096
#define HID 512
#define HEADS 8
#define DH 64
#define EPS 1e-5f
#define MAXD 128

typedef __attribute__((ext_vector_type(8))) short bf16x8;
typedef __attribute__((ext_vector_type(4))) float f32x4;

__device__ __forceinline__ unsigned short f2bf(float f) {
    unsigned int u = __float_as_uint(f);
    unsigned int r = (u + 0x7FFFu + ((u >> 16) & 1u)) >> 16;   // RNE
    return (unsigned short)r;
}
__device__ __forceinline__ float blo(unsigned int u) {        // low bf16 -> f32
    return __uint_as_float(u << 16);
}
__device__ __forceinline__ float bhi(unsigned int u) {        // high bf16 -> f32
    return __uint_as_float(u & 0xffff0000u);
}

__device__ __forceinline__ void gld_lds16(const void* g, void* l) {
    __builtin_amdgcn_global_load_lds(
        (const __attribute__((address_space(1))) unsigned int*)g,
        (__attribute__((address_space(3))) unsigned int*)l, 16, 0, 0);
}

// ---------------------------------------------------------------------------
// bf16 MFMA GEMM: C[M x Nc] = X[M x K] @ W^T  (Wt[Nc][K] K-major)
// Proven R0/R3 single-buffer core (dbuf R1, counted-vmcnt R4, coop R5
// all neutral-or-worse -> kernel bodies are NOT where the slack lives).
// TM x 64 tile, BK=64, 256 threads = 4 waves stacked on M.
// Swizzle: global k-chunk (tid&7)^(srow&7) -> LDS slot s of row r holds
// chunk s^(r&7); read slot (half*4+lq)^(lc&7) -> conflict-free b128.
// EPI: 0 bias->bf16 ; 1 bias+relu->bf16 ; 2 bias+res(f32)->f32 + stats ;
//      4 bias+res(BN1(x1 f32) on-the-fly)->f32 + stats  (bn1 fused)
// ---------------------------------------------------------------------------
template<int TM, int EPI>
__global__ __launch_bounds__(256) void gemm_bf16(
    const unsigned short* __restrict__ Xb, const unsigned short* __restrict__ Wt,
    const float* __restrict__ bias, const float* __restrict__ res,
    float* __restrict__ outf, unsigned short* __restrict__ outb,
    float* __restrict__ sum, float* __restrict__ sumsq,
    int K, int Nc,
    const float* __restrict__ bnG, const float* __restrict__ bnB,
    const float* __restrict__ bnSt)
{
    constexpr int WM = TM / 64;                      // 2 (TM=128) or 1 (TM=64)
    __shared__ __align__(16) unsigned short As[TM * 64];
    __shared__ __align__(16) unsigned short Bs[64 * 64];

    const int tid = threadIdx.x;
    const int lane = tid & 63;
    const int wv = tid >> 6;
    const int m0 = blockIdx.y * TM, n0 = blockIdx.x * 64;
    const int lc = lane & 15, lq = lane >> 4;
    const int rowbase = wv * (WM * 16);

    const int srow = tid >> 3;                       // 0..31
    const int schunk = (tid & 7) ^ (srow & 7);       // swizzled global k-chunk
    unsigned short* ldsA = As + tid * 8;
    unsigned short* ldsB = Bs + tid * 8;
    const int rs0 = lq ^ (lc & 7);
    const int rs1 = (4 + lq) ^ (lc & 7);

    f32x4 acc[WM][4] = {};

    for (int k0 = 0; k0 < K; k0 += 64) {
        const unsigned short* gA = Xb + (size_t)(m0 + srow) * K + k0 + schunk * 8;
        const unsigned short* gB = Wt + (size_t)(n0 + srow) * K + k0 + schunk * 8;
        #pragma unroll
        for (int p = 0; p < TM / 32; ++p)
            gld_lds16(gA + (size_t)(p * 32) * K, ldsA + p * 2048);
        #pragma unroll
        for (int p = 0; p < 2; ++p)
            gld_lds16(gB + (size_t)(p * 32) * K, ldsB + p * 2048);
        __syncthreads();

        #pragma unroll
        for (int hh = 0; hh < 2; ++hh) {
            const int rs = hh ? rs1 : rs0;
            bf16x8 af[WM], bfr[4];
            #pragma unroll
            for (int i = 0; i < WM; ++i)
                af[i] = *(const bf16x8*)&As[(rowbase + i * 16 + lc) * 64 + rs * 8];
            #pragma unroll
            for (int j = 0; j < 4; ++j)
                bfr[j] = *(const bf16x8*)&Bs[(j * 16 + lc) * 64 + rs * 8];
            #pragma unroll
            for (int i = 0; i < WM; ++i)
                #pragma unroll
                for (int j = 0; j < 4; ++j)
                    acc[i][j] = __builtin_amdgcn_mfma_f32_16x16x32_bf16(af[i], bfr[j], acc[i][j], 0, 0, 0);
        }
        __syncthreads();
    }

    float cs[4] = {}, css[4] = {};
    #pragma unroll
    for (int i = 0; i < WM; ++i) {
        #pragma unroll
        for (int j = 0; j < 4; ++j) {
            const int gr0 = m0 + rowbase + i * 16 + lq * 4;
            const int gc = n0 + j * 16 + lc;
            const float bi = bias[gc];
            float aj = 0.f, bj = 0.f;
            if (EPI == 4) {
                // recompute BN1 affine for this column from raw stats
                float mm = bnSt[gc] * (1.0f / N_NODES);
                float rr = rsqrtf(bnSt[512 + gc] * (1.0f / N_NODES) - mm * mm + EPS);
                aj = bnG[gc] * rr;
                bj = fmaf(-mm, aj, bnB[gc]);
            }
            #pragma unroll
            for (int r = 0; r < 4; ++r) {
                float val = acc[i][j][r] + bi;
                size_t off = (size_t)(gr0 + r) * Nc + gc;
                if (EPI == 0)      outb[off] = f2bf(val);
                else if (EPI == 1) outb[off] = f2bf(fmaxf(val, 0.f));
                else {
                    if (EPI == 2) val += res[off];
                    else          val += fmaf(res[off], aj, bj);   // EPI 4
                    outf[off] = val;
                    cs[j] += val; css[j] += val * val;
                }
            }
        }
    }
    if (EPI >= 2) {
        #pragma unroll
        for (int j = 0; j < 4; ++j) {
            float s = cs[j], ss = css[j];
            s += __shfl_xor(s, 16); s += __shfl_xor(s, 32);
            ss += __shfl_xor(ss, 16); ss += __shfl_xor(ss, 32);
            if (lq == 0) {
                const int gc = n0 + j * 16 + lc;
                atomicAdd(&sum[gc], s);
                atomicAdd(&sumsq[gc], ss);
            }
        }
    }
}

// ---------------------------------------------------------------------------
// FFN1 with BN1 fused into the A-staging: A = BN1(x1) computed on the fly.
// Per-column affine a[c] = g*rs, b[c] = bias - m*g*rs precomputed into LDS
// once per block; staging loads x1 (f32, reg-staged), applies the affine,
// packs bf16, writes to the SAME swizzled layout the MFMA loop reads.
// Epilogue: bias + relu -> bf16 (t_b). Removes the bn1_apply dispatch and
// the xb1_b buffer entirely.
// ---------------------------------------------------------------------------
__global__ __launch_bounds__(256) void gemm_ffn1(
    const float* __restrict__ x1, const unsigned short* __restrict__ Wt,
    const float* __restrict__ bias, const float* __restrict__ g,
    const float* __restrict__ bb, const float* __restrict__ st,
    unsigned short* __restrict__ outb)
{
    constexpr int TM = 128, WM = 2;
    __shared__ __align__(16) unsigned short As[TM * 64];
    __shared__ __align__(16) unsigned short Bs[64 * 64];
    __shared__ float sA[512];
    __shared__ float sB[512];

    const int tid = threadIdx.x;
    const int lane = tid & 63;
    const int wv = tid >> 6;
    const int m0 = blockIdx.y * TM, n0 = blockIdx.x * 64;
    const int lc = lane & 15, lq = lane >> 4;
    const int rowbase = wv * (WM * 16);
    const int srow = tid >> 3;
    const int schunk = (tid & 7) ^ (srow & 7);
    unsigned short* ldsB = Bs + tid * 8;
    const int rs0 = lq ^ (lc & 7);
    const int rs1 = (4 + lq) ^ (lc & 7);

    // per-column BN1 affine from raw stats
    for (int c = tid; c < 512; c += 256) {
        float m = st[c] * (1.0f / N_NODES);
        float r = rsqrtf(st[512 + c] * (1.0f / N_NODES) - m * m + EPS);
        float a = g[c] * r;
        sA[c] = a;
        sB[c] = fmaf(-m, a, bb[c]);
    }
    __syncthreads();

    f32x4 acc[WM][4] = {};

    for (int k0 = 0; k0 < 512; k0 += 64) {
        // B staging (async, unchanged)
        const unsigned short* gB = Wt + (size_t)(n0 + srow) * 512 + k0 + schunk * 8;
        #pragma unroll
        for (int p = 0; p < 2; ++p)
            gld_lds16(gB + (size_t)(p * 32) * 512, ldsB + p * 2048);

        // A staging: reg-load x1, apply BN affine, pack bf16, LDS write
        const int c0 = k0 + schunk * 8;
        const float4 a0 = *(const float4*)&sA[c0];
        const float4 a1 = *(const float4*)&sA[c0 + 4];
        const float4 o0 = *(const float4*)&sB[c0];
        const float4 o1 = *(const float4*)&sB[c0 + 4];
        #pragma unroll
        for (int p = 0; p < 4; ++p) {
            const float* gx = x1 + (size_t)(m0 + p * 32 + srow) * 512 + c0;
            const float4 v0 = *(const float4*)gx;
            const float4 v1 = *(const float4*)(gx + 4);
            const float y0 = fmaf(v0.x, a0.x, o0.x), y1 = fmaf(v0.y, a0.y, o0.y);
            const float y2 = fmaf(v0.z, a0.z, o0.z), y3 = fmaf(v0.w, a0.w, o0.w);
            const float y4 = fmaf(v1.x, a1.x, o1.x), y5 = fmaf(v1.y, a1.y, o1.y);
            const float y6 = fmaf(v1.z, a1.z, o1.z), y7 = fmaf(v1.w, a1.w, o1.w);
            uint4 w;
            w.x = (unsigned int)f2bf(y0) | ((unsigned int)f2bf(y1) << 16);
            w.y = (unsigned int)f2bf(y2) | ((unsigned int)f2bf(y3) << 16);
            w.z = (unsigned int)f2bf(y4) | ((unsigned int)f2bf(y5) << 16);
            w.w = (unsigned int)f2bf(y6) | ((unsigned int)f2bf(y7) << 16);
            *(uint4*)&As[tid * 8 + p * 2048] = w;
        }
        __syncthreads();

        #pragma unroll
        for (int hh = 0; hh < 2; ++hh) {
            const int rs = hh ? rs1 : rs0;
            bf16x8 af[WM], bfr[4];
            #pragma unroll
            for (int i = 0; i < WM; ++i)
                af[i] = *(const bf16x8*)&As[(rowbase + i * 16 + lc) * 64 + rs * 8];
            #pragma unroll
            for (int j = 0; j < 4; ++j)
                bfr[j] = *(const bf16x8*)&Bs[(j * 16 + lc) * 64 + rs * 8];
            #pragma unroll
            for (int i = 0; i < WM; ++i)
                #pragma unroll
                for (int j = 0; j < 4; ++j)
                    acc[i][j] = __builtin_amdgcn_mfma_f32_16x16x32_bf16(af[i], bfr[j], acc[i][j], 0, 0, 0);
        }
        __syncthreads();
    }

    // epilogue: bias + relu -> bf16
    #pragma unroll
    for (int i = 0; i < WM; ++i) {
        #pragma unroll
        for (int j = 0; j < 4; ++j) {
            const int gr0 = m0 + rowbase + i * 16 + lq * 4;
            const int gc = n0 + j * 16 + lc;
            const float bi = bias[gc];
            #pragma unroll
            for (int r = 0; r < 4; ++r) {
                float val = acc[i][j][r] + bi;
                outb[(size_t)(gr0 + r) * 1024 + gc] = f2bf(fmaxf(val, 0.f));
            }
        }
    }
}

// ---------------------------------------------------------------------------
// Fused prep: z=0..5 weight transposes, z=6 h->bf16, z=7 bias concat + zero,
// z=8 adjacency CSR build (rides prep's idle HBM).
// ---------------------------------------------------------------------------
__global__ __launch_bounds__(256) void prep_all(
    const float* __restrict__ Wq, const float* __restrict__ Wk,
    const float* __restrict__ Wv, const float* __restrict__ Wo,
    const float* __restrict__ W1, const float* __restrict__ W2,
    const float* __restrict__ h,
    const float* __restrict__ bq, const float* __restrict__ bk,
    const float* __restrict__ bv,
    unsigned short* __restrict__ wqkvT, unsigned short* __restrict__ woT,
    unsigned short* __restrict__ w1T, unsigned short* __restrict__ w2T,
    unsigned int* __restrict__ hb, float* __restrict__ bqkv,
    float* __restrict__ st,
    const float* __restrict__ Adj, int* __restrict__ adjIdx,
    int* __restrict__ adjCnt)
{
    const int z = blockIdx.z;
    if (z < 6) {
        const float* in; unsigned short* out; int R, C;
        switch (z) {
            case 0: in = Wq; out = wqkvT;          R = 512;  C = 512;  break;
            case 1: in = Wk; out = wqkvT + 262144; R = 512;  C = 512;  break;
            case 2: in = Wv; out = wqkvT + 524288; R = 512;  C = 512;  break;
            case 3: in = Wo; out = woT;            R = 512;  C = 512;  break;
            case 4: in = W1; out = w1T;            R = 512;  C = 1024; break;
            default: in = W2; out = w2T;           R = 1024; C = 512;  break;
        }
        const int bc = blockIdx.x * 32, br = blockIdx.y * 32;
        if (bc >= C || br >= R) return;
        __shared__ float tile[32][33];
        const int tx = threadIdx.x & 31, ty = threadIdx.x >> 5;
        #pragma unroll
        for (int r = ty; r < 32; r += 8)
            tile[r][tx] = in[(size_t)(br + r) * C + bc + tx];
        __syncthreads();
        #pragma unroll
        for (int r = ty; r < 32; r += 8)
            out[(size_t)(bc + r) * R + br + tx] = f2bf(tile[tx][r]);
    } else if (z == 6) {
        const int blk = blockIdx.y * 32 + blockIdx.x;
        const int i = blk * 512 + threadIdx.x * 2;   // float4 index (524288 total)
        const float4* in4 = (const float4*)h;
        #pragma unroll
        for (int u = 0; u < 2; ++u) {
            float4 f = in4[i + u];
            hb[(i + u) * 2]     = (unsigned int)f2bf(f.x) | ((unsigned int)f2bf(f.y) << 16);
            hb[(i + u) * 2 + 1] = (unsigned int)f2bf(f.z) | ((unsigned int)f2bf(f.w) << 16);
        }
    } else if (z == 7) {
        const int blk = blockIdx.y * 32 + blockIdx.x;
        const int i = blk * 256 + threadIdx.x;
        if (i < 1536) bqkv[i] = i < 512 ? bq[i] : (i < 1024 ? bk[i - 512] : bv[i - 1024]);
        if (i < 2048) st[i] = 0.0f;
    } else {
        // ---- adjacency CSR build: 1024 blocks x 4 nodes, 4 waves per row ----
        const int tid = threadIdx.x;
        const int lane = tid & 63;
        const int wv4 = tid >> 6;
        __shared__ int s_cnt[4];
        const unsigned long long lt = (1ull << lane) - 1ull;
        const int blk = blockIdx.y * 32 + blockIdx.x;    // 0..1023
        #pragma unroll
        for (int it = 0; it < 4; ++it) {
            const int n = blk * 4 + it;
            const float4* r4 = (const float4*)(Adj + (size_t)n * N_NODES);
            float4 av[4];
            #pragma unroll
            for (int t = 0; t < 4; ++t)
                av[t] = r4[wv4 * 256 + t * 64 + lane];
            int cnt = 0;
            #pragma unroll
            for (int t = 0; t < 4; ++t) {
                #pragma unroll
                for (int b = 0; b < 4; ++b) {
                    float vb = (b == 0) ? av[t].x : (b == 1) ? av[t].y : (b == 2) ? av[t].z : av[t].w;
                    cnt += __popcll(__ballot(vb > 0.0f));
                }
            }
            if (lane == 0) s_cnt[wv4] = cnt;
            __syncthreads();
            int base = 0, total = 0;
            #pragma unroll
            for (int w = 0; w < 4; ++w) {
                if (w < wv4) base += s_cnt[w];
                total += s_cnt[w];
            }
            #pragma unroll
            for (int t = 0; t < 4; ++t) {
                #pragma unroll
                for (int b = 0; b < 4; ++b) {
                    float vb = (b == 0) ? av[t].x : (b == 1) ? av[t].y : (b == 2) ? av[t].z : av[t].w;
                    unsigned long long m = __ballot(vb > 0.0f);
                    if (vb > 0.0f) {
                        int p = base + __popcll(m & lt);
                        if (p < MAXD) adjIdx[n * MAXD + p] = wv4 * 1024 + t * 256 + lane * 4 + b;
                    }
                    base += __popcll(m);
                }
            }
            if (tid == 0) adjCnt[n] = total < MAXD ? total : MAXD;
            __syncthreads();   // protect s_cnt before next node iteration
        }
    }
}

// ---------------------------------------------------------------------------
// Sparse attention v6: adjacency precomputed (prep z=8). Dual-head gather
// loops with 1-deep prefetch (0 conflicts). NO bulk K/V LDS staging.
// ---------------------------------------------------------------------------
__global__ __launch_bounds__(256) void sparse_attn6(
    const int* __restrict__ adjIdx, const int* __restrict__ adjCnt,
    const unsigned short* __restrict__ qkv, unsigned short* __restrict__ o)
{
    const int n = blockIdx.x;
    const int tid = threadIdx.x;
    const int wv = tid >> 6, lane = tid & 63;

    __shared__ int s_idx[MAXD];
    __shared__ float s_p[8][MAXD];

    const int d = adjCnt[n];
    if (tid < d) s_idx[tid] = adjIdx[n * MAXD + tid];
    __syncthreads();

    // ---- scores ----
    const int jl = lane >> 3;
    const int dgs = lane & 7;
    const int jl2 = lane >> 4;
    const int dga = lane & 15;
    const int h0 = wv, h1 = wv + 4;

    const unsigned short* qp = qkv + (size_t)n * 1536 + dgs * 8;
    uint4 qa = *(const uint4*)(qp + h0 * 64);
    uint4 qb = *(const uint4*)(qp + h1 * 64);
    const float a0 = blo(qa.x), a1 = bhi(qa.x), a2 = blo(qa.y), a3 = bhi(qa.y);
    const float a4 = blo(qa.z), a5 = bhi(qa.z), a6 = blo(qa.w), a7 = bhi(qa.w);
    const float b0 = blo(qb.x), b1 = bhi(qb.x), b2 = blo(qb.y), b3 = bhi(qb.y);
    const float b4 = blo(qb.z), b5 = bhi(qb.z), b6 = blo(qb.w), b7 = bhi(qb.w);

    uint4 ka = {0, 0, 0, 0}, kb = {0, 0, 0, 0};
    if (jl < d) {
        const unsigned short* p = qkv + (size_t)s_idx[jl] * 1536 + 512 + dgs * 8;
        ka = *(const uint4*)(p + h0 * 64);
        kb = *(const uint4*)(p + h1 * 64);
    }
    for (int j0 = 0; j0 < d; j0 += 8) {
        const uint4 ca = ka, cb = kb;
        const int jn = j0 + 8 + jl;
        if (jn < d) {
            const unsigned short* p = qkv + (size_t)s_idx[jn] * 1536 + 512 + dgs * 8;
            ka = *(const uint4*)(p + h0 * 64);
            kb = *(const uint4*)(p + h1 * 64);
        }
        const int jc = j0 + jl;
        float s0 = 0.f, s1 = 0.f;
        if (jc < d) {
            s0 = a0 * blo(ca.x) + a1 * bhi(ca.x) + a2 * blo(ca.y) + a3 * bhi(ca.y)
               + a4 * blo(ca.z) + a5 * bhi(ca.z) + a6 * blo(ca.w) + a7 * bhi(ca.w);
            s1 = b0 * blo(cb.x) + b1 * bhi(cb.x) + b2 * blo(cb.y) + b3 * bhi(cb.y)
               + b4 * blo(cb.z) + b5 * bhi(cb.z) + b6 * blo(cb.w) + b7 * bhi(cb.w);
        }
        s0 += __shfl_xor(s0, 1); s1 += __shfl_xor(s1, 1);
        s0 += __shfl_xor(s0, 2); s1 += __shfl_xor(s1, 2);
        s0 += __shfl_xor(s0, 4); s1 += __shfl_xor(s1, 4);
        if (dgs == 0 && jc < d) {
            s_p[h0][jc] = s0 * 0.125f;
            s_p[h1][jc] = s1 * 0.125f;
        }
    }

    float inv0, inv1;
    #pragma unroll
    for (int hh = 0; hh < 2; ++hh) {
        float* sp = s_p[hh ? h1 : h0];
        float mx = -1e30f;
        for (int j = lane; j < d; j += 64) mx = fmaxf(mx, sp[j]);
        #pragma unroll
        for (int off = 32; off; off >>= 1) mx = fmaxf(mx, __shfl_xor(mx, off));
        float sum = 0.f;
        for (int j = lane; j < d; j += 64) {
            float e = __expf(sp[j] - mx);
            sp[j] = e;
            sum += e;
        }
        #pragma unroll
        for (int off = 32; off; off >>= 1) sum += __shfl_xor(sum, off);
        if (hh) inv1 = 1.0f / sum; else inv0 = 1.0f / sum;
    }

    float x0 = 0.f, x1 = 0.f, x2 = 0.f, x3 = 0.f;
    float y0 = 0.f, y1 = 0.f, y2 = 0.f, y3 = 0.f;
    uint2 va = {0, 0}, vb = {0, 0};
    if (jl2 < d) {
        const unsigned short* p = qkv + (size_t)s_idx[jl2] * 1536 + 1024 + dga * 4;
        va = *(const uint2*)(p + h0 * 64);
        vb = *(const uint2*)(p + h1 * 64);
    }
    for (int j0 = 0; j0 < d; j0 += 4) {
        const uint2 ca = va, cb = vb;
        const int jn = j0 + 4 + jl2;
        if (jn < d) {
            const unsigned short* p = qkv + (size_t)s_idx[jn] * 1536 + 1024 + dga * 4;
            va = *(const uint2*)(p + h0 * 64);
            vb = *(const uint2*)(p + h1 * 64);
        }
        const int jc = j0 + jl2;
        if (jc < d) {
            const float p0 = s_p[h0][jc], p1 = s_p[h1][jc];
            x0 += p0 * blo(ca.x); x1 += p0 * bhi(ca.x);
            x2 += p0 * blo(ca.y); x3 += p0 * bhi(ca.y);
            y0 += p1 * blo(cb.x); y1 += p1 * bhi(cb.x);
            y2 += p1 * blo(cb.y); y3 += p1 * bhi(cb.y);
        }
    }
    x0 += __shfl_xor(x0, 16); x0 += __shfl_xor(x0, 32);
    x1 += __shfl_xor(x1, 16); x1 += __shfl_xor(x1, 32);
    x2 += __shfl_xor(x2, 16); x2 += __shfl_xor(x2, 32);
    x3 += __shfl_xor(x3, 16); x3 += __shfl_xor(x3, 32);
    y0 += __shfl_xor(y0, 16); y0 += __shfl_xor(y0, 32);
    y1 += __shfl_xor(y1, 16); y1 += __shfl_xor(y1, 32);
    y2 += __shfl_xor(y2, 16); y2 += __shfl_xor(y2, 32);
    y3 += __shfl_xor(y3, 16); y3 += __shfl_xor(y3, 32);
    if (jl2 == 0) {
        uint2 w0, w1;
        w0.x = (unsigned int)f2bf(x0 * inv0) | ((unsigned int)f2bf(x1 * inv0) << 16);
        w0.y = (unsigned int)f2bf(x2 * inv0) | ((unsigned int)f2bf(x3 * inv0) << 16);
        w1.x = (unsigned int)f2bf(y0 * inv1) | ((unsigned int)f2bf(y1 * inv1) << 16);
        w1.y = (unsigned int)f2bf(y2 * inv1) | ((unsigned int)f2bf(y3 * inv1) << 16);
        *(uint2*)(o + (size_t)n * 512 + h0 * 64 + dga * 4) = w0;
        *(uint2*)(o + (size_t)n * 512 + h1 * 64 + dga * 4) = w1;
    }
}

// ---------------------------------------------------------------------------
// BatchNorm apply, float4. Only used for BN2 -> out (BN1 apply fused).
// ---------------------------------------------------------------------------
__global__ __launch_bounds__(256) void bn_apply4(
    const float4* __restrict__ x, const float* __restrict__ sum,
    const float* __restrict__ sumsq, const float* __restrict__ g,
    const float* __restrict__ b, float4* __restrict__ yf)
{
    const int i = blockIdx.x * 256 + threadIdx.x;
    const int c4 = i & 127;
    const float4 s4 = ((const float4*)sum)[c4];
    const float4 q4 = ((const float4*)sumsq)[c4];
    const float4 g4 = ((const float4*)g)[c4];
    const float4 b4 = ((const float4*)b)[c4];
    const float4 xv = x[i];
    const float kN = 1.0f / N_NODES;
    float4 r;
    { float m = s4.x * kN; r.x = g4.x * (xv.x - m) * rsqrtf(q4.x * kN - m * m + EPS) + b4.x; }
    { float m = s4.y * kN; r.y = g4.y * (xv.y - m) * rsqrtf(q4.y * kN - m * m + EPS) + b4.y; }
    { float m = s4.z * kN; r.z = g4.z * (xv.z - m) * rsqrtf(q4.z * kN - m * m + EPS) + b4.z; }
    { float m = s4.w * kN; r.w = g4.w * (xv.w - m) * rsqrtf(q4.w * kN - m * m + EPS) + b4.w; }
    yf[i] = r;
}

// ---------------------------------------------------------------------------

extern "C" void kernel_launch(void* const* d_in, const int* in_sizes, int n_in,
                              void* d_out, int out_size, void* d_ws, size_t ws_size,
                              hipStream_t stream)
{
    const float* A   = (const float*)d_in[0];
    const float* h   = (const float*)d_in[1];
    const float* Wq  = (const float*)d_in[2];
    const float* bq  = (const float*)d_in[3];
    const float* Wk  = (const float*)d_in[4];
    const float* bk  = (const float*)d_in[5];
    const float* Wv  = (const float*)d_in[6];
    const float* bv  = (const float*)d_in[7];
    const float* Wo  = (const float*)d_in[8];
    const float* bo  = (const float*)d_in[9];
    const float* g1  = (const float*)d_in[10];
    const float* b1g = (const float*)d_in[11];
    const float* g2  = (const float*)d_in[12];
    const float* b2g = (const float*)d_in[13];
    const float* W1  = (const float*)d_in[14];
    const float* b1  = (const float*)d_in[15];
    const float* W2  = (const float*)d_in[16];
    const float* b2  = (const float*)d_in[17];
    float* out = (float*)d_out;

    float* ws = (float*)d_ws;
    unsigned short* hb    = (unsigned short*)(ws);               // 4096x512 bf16
    unsigned short* qkvb  = (unsigned short*)(ws + 1048576);     // 4096x1536 bf16
    unsigned short* o_bf  = (unsigned short*)(ws + 4194304);     // 4096x512 bf16
    unsigned short* wqkvT = (unsigned short*)(ws + 5242880);     // 1536x512 bf16
    unsigned short* woT   = (unsigned short*)(ws + 5636096);     // 512x512 bf16
    unsigned short* w1T   = (unsigned short*)(ws + 5767168);     // 1024x512 bf16
    unsigned short* w2T   = (unsigned short*)(ws + 6029312);     // 512x1024 bf16
    unsigned short* t_b   = (unsigned short*)(ws + 6291456);     // 4096x1024 bf16
    float* x1   = ws + 8388608;                                   // 4096x512 f32
    float* x2   = ws + 10485760;                                  // 4096x512 f32
    float* bqkv = ws + 13631488;                                  // 1536
    float* st   = ws + 13633024;                                  // 2048
    // Adjacency CSR aliased into the head of the t_b region: written in
    // prep (z=8), read only by sparse_attn6, dead before FFN1 writes t_b.
    int* adjIdx = (int*)(ws + 6291456);                           // 4096x128 int
    int* adjCnt = (int*)(ws + 6815744);                           // 4096 int

    // --- fused prep (+ adjacency scan riding prep's idle HBM, z=8) ---
    prep_all<<<dim3(32, 32, 9), dim3(256), 0, stream>>>(
        Wq, Wk, Wv, Wo, W1, W2, h, bq, bk, bv,
        wqkvT, woT, w1T, w2T, (unsigned int*)hb, bqkv, st,
        A, adjIdx, adjCnt);

    // --- fused QKV projection: 768 blocks (3/CU) ---
    gemm_bf16<128, 0><<<dim3(24, 32), dim3(256), 0, stream>>>(
        hb, wqkvT, bqkv, nullptr, nullptr, qkvb, nullptr, nullptr,
        512, 1536, nullptr, nullptr, nullptr);

    // --- sparse masked attention (precomputed adjacency) ---
    sparse_attn6<<<dim3(N_NODES), dim3(256), 0, stream>>>(adjIdx, adjCnt, qkvb, o_bf);

    // --- O projection + residual(h,f32) + BN1 stats -> x1 ---
    gemm_bf16<64, 2><<<dim3(8, 64), dim3(256), 0, stream>>>(
        o_bf, woT, bo, h, x1, nullptr, st, st + 512,
        512, 512, nullptr, nullptr, nullptr);

    // --- FFN1 with BN1 fused into A-staging (bn1_apply dispatch removed) ---
    gemm_ffn1<<<dim3(16, 32), dim3(256), 0, stream>>>(
        x1, w1T, b1, g1, b1g, st, t_b);

    // --- FFN2 + residual(BN1(x1) on-the-fly) + BN2 stats -> x2 ---
    gemm_bf16<64, 4><<<dim3(8, 64), dim3(256), 0, stream>>>(
        t_b, w2T, b2, x1, x2, nullptr, st + 1024, st + 1536,
        1024, 512, g1, b1g, st);

    // --- BN2 apply -> out ---
    bn_apply4<<<dim3(2048), dim3(256), 0, stream>>>(
        (const float4*)x2, st + 1024, st + 1536, g2, b2g, (float4*)out);

    (void)in_sizes; (void)n_in; (void)out_size; (void)ws_size;
}

// Round 8
// 231.427 us; speedup vs baseline: 2.1551x; 1.0706x over previous
//
#include <hip/hip_runtime.h>

#define N_NODES 4096
#define HID 512
#define HEADS 8
#define DH 64
#define EPS 1e-5f
#define MAXD 128

typedef __attribute__((ext_vector_type(8))) short bf16x8;
typedef __attribute__((ext_vector_type(4))) float f32x4;

__device__ __forceinline__ unsigned short f2bf(float f) {
    unsigned int u = __float_as_uint(f);
    unsigned int r = (u + 0x7FFFu + ((u >> 16) & 1u)) >> 16;   // RNE
    return (unsigned short)r;
}
__device__ __forceinline__ float blo(unsigned int u) {        // low bf16 -> f32
    return __uint_as_float(u << 16);
}
__device__ __forceinline__ float bhi(unsigned int u) {        // high bf16 -> f32
    return __uint_as_float(u & 0xffff0000u);
}

__device__ __forceinline__ void gld_lds16(const void* g, void* l) {
    __builtin_amdgcn_global_load_lds(
        (const __attribute__((address_space(1))) unsigned int*)g,
        (__attribute__((address_space(3))) unsigned int*)l, 16, 0, 0);
}

// ---------------------------------------------------------------------------
// bf16 MFMA GEMM: C[M x Nc] = X[M x K] @ W^T  (Wt[Nc][K] K-major)
// TM x 64 tile, BK=64, 256 threads = 4 waves stacked on M (WM = TM/64 mfma
// row-tiles per wave). Tile-N fixed at 64 so every GEMM launches >=512
// blocks (>=2/CU) — at 1 block/CU the barrier drain stalls the whole CU
// (R5 lesson: 256-block GEMMs ran at 12.5% occupancy).
// Swizzle: global k-chunk (tid&7)^(srow&7) -> LDS slot s of row r holds
// chunk s^(r&7); read slot (half*4+lq)^(lc&7) -> conflict-free b128
// (0 SQ_LDS_BANK_CONFLICT measured).
// EPI: 0 bias->bf16 ; 1 bias+relu->bf16 ; 2 bias+res(f32)->f32 + stats ;
//      3 bias+res(bf16)->f32 + stats
// Session R1-R7 adjudications: dbuf, 3-buffer counted-vmcnt+setprio,
// cooperative mega-fusion, adjacency-plane moves, BN1 fusion — ALL neutral
// or regressions. This single-buffer structure is the proven best.
// ---------------------------------------------------------------------------
template<int TM, int EPI>
__global__ __launch_bounds__(256) void gemm_bf16(
    const unsigned short* __restrict__ Xb, const unsigned short* __restrict__ Wt,
    const float* __restrict__ bias, const float* __restrict__ res,
    const unsigned short* __restrict__ resb,
    float* __restrict__ outf, unsigned short* __restrict__ outb,
    float* __restrict__ sum, float* __restrict__ sumsq,
    int K, int Nc)
{
    constexpr int WM = TM / 64;                      // 2 (TM=128) or 1 (TM=64)
    __shared__ __align__(16) unsigned short As[TM * 64];
    __shared__ __align__(16) unsigned short Bs[64 * 64];

    const int tid = threadIdx.x;
    const int lane = tid & 63;
    const int wv = tid >> 6;
    const int m0 = blockIdx.y * TM, n0 = blockIdx.x * 64;
    const int lc = lane & 15, lq = lane >> 4;
    const int rowbase = wv * (WM * 16);

    const int srow = tid >> 3;                       // 0..31
    const int schunk = (tid & 7) ^ (srow & 7);       // swizzled global k-chunk
    unsigned short* ldsA = As + tid * 8;
    unsigned short* ldsB = Bs + tid * 8;
    const int rs0 = lq ^ (lc & 7);
    const int rs1 = (4 + lq) ^ (lc & 7);

    f32x4 acc[WM][4] = {};

    for (int k0 = 0; k0 < K; k0 += 64) {
        const unsigned short* gA = Xb + (size_t)(m0 + srow) * K + k0 + schunk * 8;
        const unsigned short* gB = Wt + (size_t)(n0 + srow) * K + k0 + schunk * 8;
        #pragma unroll
        for (int p = 0; p < TM / 32; ++p)
            gld_lds16(gA + (size_t)(p * 32) * K, ldsA + p * 2048);
        #pragma unroll
        for (int p = 0; p < 2; ++p)
            gld_lds16(gB + (size_t)(p * 32) * K, ldsB + p * 2048);
        __syncthreads();

        #pragma unroll
        for (int hh = 0; hh < 2; ++hh) {
            const int rs = hh ? rs1 : rs0;
            bf16x8 af[WM], bfr[4];
            #pragma unroll
            for (int i = 0; i < WM; ++i)
                af[i] = *(const bf16x8*)&As[(rowbase + i * 16 + lc) * 64 + rs * 8];
            #pragma unroll
            for (int j = 0; j < 4; ++j)
                bfr[j] = *(const bf16x8*)&Bs[(j * 16 + lc) * 64 + rs * 8];
            #pragma unroll
            for (int i = 0; i < WM; ++i)
                #pragma unroll
                for (int j = 0; j < 4; ++j)
                    acc[i][j] = __builtin_amdgcn_mfma_f32_16x16x32_bf16(af[i], bfr[j], acc[i][j], 0, 0, 0);
        }
        __syncthreads();
    }

    float cs[4] = {}, css[4] = {};
    #pragma unroll
    for (int i = 0; i < WM; ++i) {
        #pragma unroll
        for (int j = 0; j < 4; ++j) {
            const int gr0 = m0 + rowbase + i * 16 + lq * 4;
            const int gc = n0 + j * 16 + lc;
            const float bi = bias[gc];
            #pragma unroll
            for (int r = 0; r < 4; ++r) {
                float val = acc[i][j][r] + bi;
                size_t off = (size_t)(gr0 + r) * Nc + gc;
                if (EPI == 0)      outb[off] = f2bf(val);
                else if (EPI == 1) outb[off] = f2bf(fmaxf(val, 0.f));
                else {
                    if (EPI == 2) val += res[off];
                    else          val += blo((unsigned int)resb[off]);
                    outf[off] = val;
                    cs[j] += val; css[j] += val * val;
                }
            }
        }
    }
    if (EPI >= 2) {
        #pragma unroll
        for (int j = 0; j < 4; ++j) {
            float s = cs[j], ss = css[j];
            s += __shfl_xor(s, 16); s += __shfl_xor(s, 32);
            ss += __shfl_xor(ss, 16); ss += __shfl_xor(ss, 32);
            if (lq == 0) {
                const int gc = n0 + j * 16 + lc;
                atomicAdd(&sum[gc], s);
                atomicAdd(&sumsq[gc], ss);
            }
        }
    }
}

// ---------------------------------------------------------------------------
// Fused prep: z=0..5 weight transposes, z=6 h->bf16, z=7 bias concat + zero
// ---------------------------------------------------------------------------
__global__ __launch_bounds__(256) void prep_all(
    const float* __restrict__ Wq, const float* __restrict__ Wk,
    const float* __restrict__ Wv, const float* __restrict__ Wo,
    const float* __restrict__ W1, const float* __restrict__ W2,
    const float* __restrict__ h,
    const float* __restrict__ bq, const float* __restrict__ bk,
    const float* __restrict__ bv,
    unsigned short* __restrict__ wqkvT, unsigned short* __restrict__ woT,
    unsigned short* __restrict__ w1T, unsigned short* __restrict__ w2T,
    unsigned int* __restrict__ hb, float* __restrict__ bqkv,
    float* __restrict__ st)
{
    const int z = blockIdx.z;
    if (z < 6) {
        const float* in; unsigned short* out; int R, C;
        switch (z) {
            case 0: in = Wq; out = wqkvT;          R = 512;  C = 512;  break;
            case 1: in = Wk; out = wqkvT + 262144; R = 512;  C = 512;  break;
            case 2: in = Wv; out = wqkvT + 524288; R = 512;  C = 512;  break;
            case 3: in = Wo; out = woT;            R = 512;  C = 512;  break;
            case 4: in = W1; out = w1T;            R = 512;  C = 1024; break;
            default: in = W2; out = w2T;           R = 1024; C = 512;  break;
        }
        const int bc = blockIdx.x * 32, br = blockIdx.y * 32;
        if (bc >= C || br >= R) return;
        __shared__ float tile[32][33];
        const int tx = threadIdx.x & 31, ty = threadIdx.x >> 5;
        #pragma unroll
        for (int r = ty; r < 32; r += 8)
            tile[r][tx] = in[(size_t)(br + r) * C + bc + tx];
        __syncthreads();
        #pragma unroll
        for (int r = ty; r < 32; r += 8)
            out[(size_t)(bc + r) * R + br + tx] = f2bf(tile[tx][r]);
    } else if (z == 6) {
        const int blk = blockIdx.y * 32 + blockIdx.x;
        const int i = blk * 512 + threadIdx.x * 2;   // float4 index (524288 total)
        const float4* in4 = (const float4*)h;
        #pragma unroll
        for (int u = 0; u < 2; ++u) {
            float4 f = in4[i + u];
            hb[(i + u) * 2]     = (unsigned int)f2bf(f.x) | ((unsigned int)f2bf(f.y) << 16);
            hb[(i + u) * 2 + 1] = (unsigned int)f2bf(f.z) | ((unsigned int)f2bf(f.w) << 16);
        }
    } else {
        const int blk = blockIdx.y * 32 + blockIdx.x;
        const int i = blk * 256 + threadIdx.x;
        if (i < 1536) bqkv[i] = i < 512 ? bq[i] : (i < 1024 ? bk[i - 512] : bv[i - 1024]);
        if (i < 2048) st[i] = 0.0f;
    }
}

// ---------------------------------------------------------------------------
// Sparse attention v5 (best-measured: 47us, 0 conflicts, occupancy 65%).
// Inline adjacency build + dual-head gather loops with 1-deep prefetch.
// NO bulk K/V LDS staging (v3's 1-block/CU cliff: 123us vs 65us).
// ---------------------------------------------------------------------------
__global__ __launch_bounds__(256) void sparse_attn5(
    const float* __restrict__ A, const unsigned short* __restrict__ qkv,
    unsigned short* __restrict__ o)
{
    const int n = blockIdx.x;
    const int tid = threadIdx.x;
    const int wv = tid >> 6, lane = tid & 63;

    __shared__ int s_idx[MAXD];
    __shared__ float s_p[8][MAXD];
    __shared__ int s_cnt[4];

    // ---- Phase A: inline adjacency ----
    const float4* r4 = (const float4*)(A + (size_t)n * N_NODES);
    float4 av[4];
    #pragma unroll
    for (int t = 0; t < 4; ++t)
        av[t] = r4[wv * 256 + t * 64 + lane];

    const unsigned long long lt = (1ull << lane) - 1ull;
    int cnt = 0;
    #pragma unroll
    for (int t = 0; t < 4; ++t) {
        #pragma unroll
        for (int b = 0; b < 4; ++b) {
            float vb = (b == 0) ? av[t].x : (b == 1) ? av[t].y : (b == 2) ? av[t].z : av[t].w;
            cnt += __popcll(__ballot(vb > 0.0f));
        }
    }
    if (lane == 0) s_cnt[wv] = cnt;
    __syncthreads();
    int base = 0, total = 0;
    #pragma unroll
    for (int w = 0; w < 4; ++w) {
        if (w < wv) base += s_cnt[w];
        total += s_cnt[w];
    }
    const int d = total < MAXD ? total : MAXD;
    #pragma unroll
    for (int t = 0; t < 4; ++t) {
        #pragma unroll
        for (int b = 0; b < 4; ++b) {
            float vb = (b == 0) ? av[t].x : (b == 1) ? av[t].y : (b == 2) ? av[t].z : av[t].w;
            unsigned long long m = __ballot(vb > 0.0f);
            if (vb > 0.0f) {
                int p = base + __popcll(m & lt);
                if (p < MAXD) s_idx[p] = wv * 1024 + t * 256 + lane * 4 + b;
            }
            base += __popcll(m);
        }
    }
    __syncthreads();

    // ---- Phase B: attention ----
    const int jl = lane >> 3;
    const int dgs = lane & 7;
    const int jl2 = lane >> 4;
    const int dga = lane & 15;
    const int h0 = wv, h1 = wv + 4;

    const unsigned short* qp = qkv + (size_t)n * 1536 + dgs * 8;
    uint4 qa = *(const uint4*)(qp + h0 * 64);
    uint4 qb = *(const uint4*)(qp + h1 * 64);
    const float a0 = blo(qa.x), a1 = bhi(qa.x), a2 = blo(qa.y), a3 = bhi(qa.y);
    const float a4 = blo(qa.z), a5 = bhi(qa.z), a6 = blo(qa.w), a7 = bhi(qa.w);
    const float b0 = blo(qb.x), b1 = bhi(qb.x), b2 = blo(qb.y), b3 = bhi(qb.y);
    const float b4 = blo(qb.z), b5 = bhi(qb.z), b6 = blo(qb.w), b7 = bhi(qb.w);

    uint4 ka = {0, 0, 0, 0}, kb = {0, 0, 0, 0};
    if (jl < d) {
        const unsigned short* p = qkv + (size_t)s_idx[jl] * 1536 + 512 + dgs * 8;
        ka = *(const uint4*)(p + h0 * 64);
        kb = *(const uint4*)(p + h1 * 64);
    }
    for (int j0 = 0; j0 < d; j0 += 8) {
        const uint4 ca = ka, cb = kb;
        const int jn = j0 + 8 + jl;
        if (jn < d) {
            const unsigned short* p = qkv + (size_t)s_idx[jn] * 1536 + 512 + dgs * 8;
            ka = *(const uint4*)(p + h0 * 64);
            kb = *(const uint4*)(p + h1 * 64);
        }
        const int jc = j0 + jl;
        float s0 = 0.f, s1 = 0.f;
        if (jc < d) {
            s0 = a0 * blo(ca.x) + a1 * bhi(ca.x) + a2 * blo(ca.y) + a3 * bhi(ca.y)
               + a4 * blo(ca.z) + a5 * bhi(ca.z) + a6 * blo(ca.w) + a7 * bhi(ca.w);
            s1 = b0 * blo(cb.x) + b1 * bhi(cb.x) + b2 * blo(cb.y) + b3 * bhi(cb.y)
               + b4 * blo(cb.z) + b5 * bhi(cb.z) + b6 * blo(cb.w) + b7 * bhi(cb.w);
        }
        s0 += __shfl_xor(s0, 1); s1 += __shfl_xor(s1, 1);
        s0 += __shfl_xor(s0, 2); s1 += __shfl_xor(s1, 2);
        s0 += __shfl_xor(s0, 4); s1 += __shfl_xor(s1, 4);
        if (dgs == 0 && jc < d) {
            s_p[h0][jc] = s0 * 0.125f;
            s_p[h1][jc] = s1 * 0.125f;
        }
    }

    float inv0, inv1;
    #pragma unroll
    for (int hh = 0; hh < 2; ++hh) {
        float* sp = s_p[hh ? h1 : h0];
        float mx = -1e30f;
        for (int j = lane; j < d; j += 64) mx = fmaxf(mx, sp[j]);
        #pragma unroll
        for (int off = 32; off; off >>= 1) mx = fmaxf(mx, __shfl_xor(mx, off));
        float sum = 0.f;
        for (int j = lane; j < d; j += 64) {
            float e = __expf(sp[j] - mx);
            sp[j] = e;
            sum += e;
        }
        #pragma unroll
        for (int off = 32; off; off >>= 1) sum += __shfl_xor(sum, off);
        if (hh) inv1 = 1.0f / sum; else inv0 = 1.0f / sum;
    }

    float x0 = 0.f, x1 = 0.f, x2 = 0.f, x3 = 0.f;
    float y0 = 0.f, y1 = 0.f, y2 = 0.f, y3 = 0.f;
    uint2 va = {0, 0}, vb = {0, 0};
    if (jl2 < d) {
        const unsigned short* p = qkv + (size_t)s_idx[jl2] * 1536 + 1024 + dga * 4;
        va = *(const uint2*)(p + h0 * 64);
        vb = *(const uint2*)(p + h1 * 64);
    }
    for (int j0 = 0; j0 < d; j0 += 4) {
        const uint2 ca = va, cb = vb;
        const int jn = j0 + 4 + jl2;
        if (jn < d) {
            const unsigned short* p = qkv + (size_t)s_idx[jn] * 1536 + 1024 + dga * 4;
            va = *(const uint2*)(p + h0 * 64);
            vb = *(const uint2*)(p + h1 * 64);
        }
        const int jc = j0 + jl2;
        if (jc < d) {
            const float p0 = s_p[h0][jc], p1 = s_p[h1][jc];
            x0 += p0 * blo(ca.x); x1 += p0 * bhi(ca.x);
            x2 += p0 * blo(ca.y); x3 += p0 * bhi(ca.y);
            y0 += p1 * blo(cb.x); y1 += p1 * bhi(cb.x);
            y2 += p1 * blo(cb.y); y3 += p1 * bhi(cb.y);
        }
    }
    x0 += __shfl_xor(x0, 16); x0 += __shfl_xor(x0, 32);
    x1 += __shfl_xor(x1, 16); x1 += __shfl_xor(x1, 32);
    x2 += __shfl_xor(x2, 16); x2 += __shfl_xor(x2, 32);
    x3 += __shfl_xor(x3, 16); x3 += __shfl_xor(x3, 32);
    y0 += __shfl_xor(y0, 16); y0 += __shfl_xor(y0, 32);
    y1 += __shfl_xor(y1, 16); y1 += __shfl_xor(y1, 32);
    y2 += __shfl_xor(y2, 16); y2 += __shfl_xor(y2, 32);
    y3 += __shfl_xor(y3, 16); y3 += __shfl_xor(y3, 32);
    if (jl2 == 0) {
        uint2 w0, w1;
        w0.x = (unsigned int)f2bf(x0 * inv0) | ((unsigned int)f2bf(x1 * inv0) << 16);
        w0.y = (unsigned int)f2bf(x2 * inv0) | ((unsigned int)f2bf(x3 * inv0) << 16);
        w1.x = (unsigned int)f2bf(y0 * inv1) | ((unsigned int)f2bf(y1 * inv1) << 16);
        w1.y = (unsigned int)f2bf(y2 * inv1) | ((unsigned int)f2bf(y3 * inv1) << 16);
        *(uint2*)(o + (size_t)n * 512 + h0 * 64 + dga * 4) = w0;
        *(uint2*)(o + (size_t)n * 512 + h1 * 64 + dga * 4) = w1;
    }
}

// ---------------------------------------------------------------------------
// BatchNorm apply, float4 (stats fused in the preceding GEMM epilogue).
// yf / yb each optional (uniform null check).
// ---------------------------------------------------------------------------
__global__ __launch_bounds__(256) void bn_apply4(
    const float4* __restrict__ x, const float* __restrict__ sum,
    const float* __restrict__ sumsq, const float* __restrict__ g,
    const float* __restrict__ b, float4* __restrict__ yf,
    uint2* __restrict__ yb)
{
    const int i = blockIdx.x * 256 + threadIdx.x;
    const int c4 = i & 127;
    const float4 s4 = ((const float4*)sum)[c4];
    const float4 q4 = ((const float4*)sumsq)[c4];
    const float4 g4 = ((const float4*)g)[c4];
    const float4 b4 = ((const float4*)b)[c4];
    const float4 xv = x[i];
    const float kN = 1.0f / N_NODES;
    float4 r;
    { float m = s4.x * kN; r.x = g4.x * (xv.x - m) * rsqrtf(q4.x * kN - m * m + EPS) + b4.x; }
    { float m = s4.y * kN; r.y = g4.y * (xv.y - m) * rsqrtf(q4.y * kN - m * m + EPS) + b4.y; }
    { float m = s4.z * kN; r.z = g4.z * (xv.z - m) * rsqrtf(q4.z * kN - m * m + EPS) + b4.z; }
    { float m = s4.w * kN; r.w = g4.w * (xv.w - m) * rsqrtf(q4.w * kN - m * m + EPS) + b4.w; }
    if (yf) yf[i] = r;
    if (yb) {
        uint2 p;
        p.x = (unsigned int)f2bf(r.x) | ((unsigned int)f2bf(r.y) << 16);
        p.y = (unsigned int)f2bf(r.z) | ((unsigned int)f2bf(r.w) << 16);
        yb[i] = p;
    }
}

// ---------------------------------------------------------------------------

extern "C" void kernel_launch(void* const* d_in, const int* in_sizes, int n_in,
                              void* d_out, int out_size, void* d_ws, size_t ws_size,
                              hipStream_t stream)
{
    const float* A   = (const float*)d_in[0];
    const float* h   = (const float*)d_in[1];
    const float* Wq  = (const float*)d_in[2];
    const float* bq  = (const float*)d_in[3];
    const float* Wk  = (const float*)d_in[4];
    const float* bk  = (const float*)d_in[5];
    const float* Wv  = (const float*)d_in[6];
    const float* bv  = (const float*)d_in[7];
    const float* Wo  = (const float*)d_in[8];
    const float* bo  = (const float*)d_in[9];
    const float* g1  = (const float*)d_in[10];
    const float* b1g = (const float*)d_in[11];
    const float* g2  = (const float*)d_in[12];
    const float* b2g = (const float*)d_in[13];
    const float* W1  = (const float*)d_in[14];
    const float* b1  = (const float*)d_in[15];
    const float* W2  = (const float*)d_in[16];
    const float* b2  = (const float*)d_in[17];
    float* out = (float*)d_out;

    float* ws = (float*)d_ws;
    unsigned short* hb    = (unsigned short*)(ws);               // 4096x512 bf16
    unsigned short* qkvb  = (unsigned short*)(ws + 1048576);     // 4096x1536 bf16
    unsigned short* o_bf  = (unsigned short*)(ws + 4194304);     // 4096x512 bf16
    unsigned short* wqkvT = (unsigned short*)(ws + 5242880);     // 1536x512 bf16
    unsigned short* woT   = (unsigned short*)(ws + 5636096);     // 512x512 bf16
    unsigned short* w1T   = (unsigned short*)(ws + 5767168);     // 1024x512 bf16
    unsigned short* w2T   = (unsigned short*)(ws + 6029312);     // 512x1024 bf16
    unsigned short* t_b   = (unsigned short*)(ws + 6291456);     // 4096x1024 bf16
    float* x1   = ws + 8388608;                                   // 4096x512 f32
    float* x2   = ws + 10485760;                                  // 4096x512 f32
    unsigned short* xb1_b = (unsigned short*)(ws + 12582912);    // 4096x512 bf16
    float* bqkv = ws + 13631488;                                  // 1536
    float* st   = ws + 13633024;                                  // 2048

    // --- fused prep ---
    prep_all<<<dim3(32, 32, 8), dim3(256), 0, stream>>>(
        Wq, Wk, Wv, Wo, W1, W2, h, bq, bk, bv,
        wqkvT, woT, w1T, w2T, (unsigned int*)hb, bqkv, st);

    // --- fused QKV projection: 768 blocks (3/CU) ---
    gemm_bf16<128, 0><<<dim3(24, 32), dim3(256), 0, stream>>>(
        hb, wqkvT, bqkv, nullptr, nullptr, nullptr, qkvb, nullptr, nullptr, 512, 1536);

    // --- sparse masked attention (inline adjacency) ---
    sparse_attn5<<<dim3(N_NODES), dim3(256), 0, stream>>>(A, qkvb, o_bf);

    // --- O projection + residual(h,f32) + BN1 stats: 512 blocks (2/CU) ---
    gemm_bf16<64, 2><<<dim3(8, 64), dim3(256), 0, stream>>>(
        o_bf, woT, bo, h, nullptr, x1, nullptr, st, st + 512, 512, 512);

    // --- BN1 apply -> bf16 only (FFN2 residual is bf16; saves fp32 RT) ---
    bn_apply4<<<dim3(2048), dim3(256), 0, stream>>>(
        (const float4*)x1, st, st + 512, g1, b1g, nullptr, (uint2*)xb1_b);

    // --- FFN1: 512 blocks (2/CU) ---
    gemm_bf16<128, 1><<<dim3(16, 32), dim3(256), 0, stream>>>(
        xb1_b, w1T, b1, nullptr, nullptr, nullptr, t_b, nullptr, nullptr, 512, 1024);

    // --- FFN2 + residual(xb1,bf16) + BN2 stats: 512 blocks (2/CU) ---
    gemm_bf16<64, 3><<<dim3(8, 64), dim3(256), 0, stream>>>(
        t_b, w2T, b2, nullptr, xb1_b, x2, nullptr, st + 1024, st + 1536, 1024, 512);

    // --- BN2 apply -> out ---
    bn_apply4<<<dim3(2048), dim3(256), 0, stream>>>(
        (const float4*)x2, st + 1024, st + 1536, g2, b2g, (float4*)out, nullptr);

    (void)in_sizes; (void)n_in; (void)out_size; (void)ws_size;
}